// Round 1
// baseline (238.545 us; speedup 1.0000x reference)
//
#include <hip/hip_runtime.h>
#include <stdint.h>

// Problem constants: B=2048, C=200, F=32, H=256. All tensors fp32 in/out.
// M = B*C = 409600 rows of 32 features, contiguous in x.
#define B_CNT  2048
#define C_CNT  200
#define M_ROWS (B_CNT * C_CNT)
#define RPB    8                       // batch rows per prep block
#define PREP_MAIN (B_CNT / RPB)        // 256 blocks for sinflow/iinflow

typedef __attribute__((ext_vector_type(8))) short bf16x8;   // 8 bf16 = 4 VGPRs
typedef __attribute__((ext_vector_type(4))) float f32x4;

// round-to-nearest-even f32 -> bf16 bits
__device__ __forceinline__ ushort f2bf(float f) {
    uint32_t u = __float_as_uint(f);
    u += 0x7fffu + ((u >> 16) & 1u);
    return (ushort)(u >> 16);
}

__device__ __forceinline__ f32x4 mfma16(bf16x8 a, bf16x8 b, f32x4 c) {
    return __builtin_amdgcn_mfma_f32_16x16x32_bf16(a, b, c, 0, 0, 0);
}

__device__ __forceinline__ bf16x8 pack8(float4 a, float4 b) {
    bf16x8 r;
    r[0] = (short)f2bf(a.x); r[1] = (short)f2bf(a.y);
    r[2] = (short)f2bf(a.z); r[3] = (short)f2bf(a.w);
    r[4] = (short)f2bf(b.x); r[5] = (short)f2bf(b.y);
    r[6] = (short)f2bf(b.z); r[7] = (short)f2bf(b.w);
    return r;
}

// ---------------------------------------------------------------------------
// Prep v2 — minimal work only:
//   blocks [0,256):    8 batch rows each. Strided gather of S/I (8B per 128B
//                      line, L3-warm) -> LDS, then sin/iin = S@T, I@T with
//                      16 fp32 FMA per (L2-hot) T load. Same fp32 accumulation
//                      order as before -> bitwise-identical sinW/iinW.
//   blocks [256,512):  W2^T -> bf16 (writes coalesced)
//   blocks [512,544):  W1^T -> bf16
// No xb16 copy, no full pass over x, no Sc/Ic arrays.
// ---------------------------------------------------------------------------
__global__ __launch_bounds__(256) void prep_kernel(
    const float* __restrict__ x, const float* __restrict__ T,
    const float* __restrict__ W1, const float* __restrict__ W2,
    float* __restrict__ sinW, float* __restrict__ iinW,
    ushort* __restrict__ W1t, ushort* __restrict__ W2t) {
    int blk = blockIdx.x, t = threadIdx.x;
    if (blk < PREP_MAIN) {
        __shared__ float Sr[C_CNT][RPB];   // [country][row-in-group]
        __shared__ float Ir[C_CNT][RPB];
        if (t < C_CNT) {
#pragma unroll
            for (int r = 0; r < RPB; ++r) {
                const float2 si =
                    *(const float2*)(x + (size_t)(blk * RPB + r) * 6400 + t * 32);
                Sr[t][r] = si.x;
                Ir[t][r] = si.y;
            }
        }
        __syncthreads();
        if (t < C_CNT) {
            float as[RPB], ai[RPB];
#pragma unroll
            for (int r = 0; r < RPB; ++r) { as[r] = 0.f; ai[r] = 0.f; }
            for (int cp = 0; cp < C_CNT; ++cp) {
                float tv = T[cp * C_CNT + t];   // coalesced over t, L2-hot
#pragma unroll
                for (int r = 0; r < RPB; ++r) {
                    as[r] = fmaf(Sr[cp][r], tv, as[r]);   // uniform LDS broadcast
                    ai[r] = fmaf(Ir[cp][r], tv, ai[r]);
                }
            }
#pragma unroll
            for (int r = 0; r < RPB; ++r) {
                sinW[(size_t)(blk * RPB + r) * C_CNT + t] = as[r];
                iinW[(size_t)(blk * RPB + r) * C_CNT + t] = ai[r];
            }
        }
    } else if (blk < PREP_MAIN + 256) {
        int n = blk - PREP_MAIN;                      // one n2 row per block
        W2t[n * 256 + t] = f2bf(W2[t * 256 + n]);     // write coalesced
    } else {
        int idx = (blk - PREP_MAIN - 256) * 256 + t;  // 0..8191
        int n = idx >> 5, k = idx & 31;
        W1t[idx] = f2bf(W1[k * 256 + n]);
    }
}

// ---------------------------------------------------------------------------
// Fused MLP kernel. One block = 64 rows, 4 waves (wave w owns n in [64w,64w+64)).
// GEMM1: h1^T = W1t(A) * x^T(B, packed in-register from fp32);
// GEMM2: h2^T = W2t(A) * h1^T(B from LDS); GEMM3: in-register dot with W3
// + shuffle/LDS reduce. Epilogue reads S/I directly from x (L1-hot lines —
// GEMM1 just read them).
// MFMA 16x16x32 frags: A[m=lane&15][k=q*8+j], B[k=q*8+j][n=lane&15],
// C/D col=lane&15, row=q*4+reg.
// ---------------------------------------------------------------------------
__global__ __launch_bounds__(256, 4) void mlp_kernel(
    const float* __restrict__ x,
    const float* __restrict__ T,
    const float* __restrict__ b1,
    const float* __restrict__ b2,
    const float* __restrict__ W3,
    const float* __restrict__ b3,
    const ushort* __restrict__ W1t,   // [256][32]  bf16, n1-major
    const ushort* __restrict__ W2t,   // [256][256] bf16, n2-major
    const float* __restrict__ sinW, const float* __restrict__ iinW,
    float* __restrict__ out) {
    constexpr int RS = 264;  // h1 row stride: 256+8, rows 16B-aligned, pad kills conflicts
    __shared__ ushort h1s[64 * RS];          // 33792 B
    __shared__ float b1f[256], b2f[256], w3f[256];
    __shared__ float lamb_part[4][64];

    const int tid  = threadIdx.x;
    const int w    = tid >> 6;
    const int lane = tid & 63;
    const int L    = lane & 15;
    const int q    = lane >> 4;
    const int m0   = blockIdx.x * 64;

    b1f[tid] = b1[tid];
    b2f[tid] = b2[tid];
    w3f[tid] = W3[tid];

    // ---- GEMM1 (K=32): A from bf16 W1t, B packed in-register from fp32 x ----
    bf16x8 aw[4], bx[4];
#pragma unroll
    for (int i = 0; i < 4; ++i) {
        int n1 = 64 * w + i * 16 + L;
        aw[i] = *(const bf16x8*)(W1t + n1 * 32 + q * 8);
        const float4* xr = (const float4*)(x + (size_t)(m0 + i * 16 + L) * 32 + q * 8);
        bx[i] = pack8(xr[0], xr[1]);
    }
    f32x4 acc1[4][4];
#pragma unroll
    for (int i1 = 0; i1 < 4; ++i1)
#pragma unroll
        for (int im = 0; im < 4; ++im)
            acc1[i1][im] = mfma16(aw[i1], bx[im], (f32x4){0.f, 0.f, 0.f, 0.f});

    __syncthreads();  // b1f visible; h1s not yet read

    // fp32 bias + relu, one bf16 rounding; 4 consecutive n1 -> ds_write_b64
#pragma unroll
    for (int i1 = 0; i1 < 4; ++i1) {
        int n1b = 64 * w + i1 * 16 + q * 4;
#pragma unroll
        for (int im = 0; im < 4; ++im) {
            int m = im * 16 + L;
            float v0 = fmaxf(acc1[i1][im][0] + b1f[n1b + 0], 0.f);
            float v1 = fmaxf(acc1[i1][im][1] + b1f[n1b + 1], 0.f);
            float v2 = fmaxf(acc1[i1][im][2] + b1f[n1b + 2], 0.f);
            float v3 = fmaxf(acc1[i1][im][3] + b1f[n1b + 3], 0.f);
            uint2 pk;
            pk.x = (uint32_t)f2bf(v0) | ((uint32_t)f2bf(v1) << 16);
            pk.y = (uint32_t)f2bf(v2) | ((uint32_t)f2bf(v3) << 16);
            *reinterpret_cast<uint2*>(&h1s[m * RS + n1b]) = pk;
        }
    }
    __syncthreads();

    // ---- GEMM2 (K=256, 8 k-chunks): A from bf16 W2t (L2-hot), B from LDS ----
    f32x4 acc2[4][4];
#pragma unroll
    for (int i2 = 0; i2 < 4; ++i2)
#pragma unroll
        for (int im = 0; im < 4; ++im) acc2[i2][im] = (f32x4){0.f, 0.f, 0.f, 0.f};

#pragma unroll
    for (int kc = 0; kc < 8; ++kc) {
        bf16x8 a2[4], bh[4];
#pragma unroll
        for (int i2 = 0; i2 < 4; ++i2) {
            int n2 = 64 * w + i2 * 16 + L;
            a2[i2] = *(const bf16x8*)(W2t + n2 * 256 + kc * 32 + q * 8);
        }
#pragma unroll
        for (int im = 0; im < 4; ++im) {
            int m = im * 16 + L;
            bh[im] = *(const bf16x8*)(&h1s[m * RS + kc * 32 + q * 8]);  // ds_read_b128
        }
#pragma unroll
        for (int i2 = 0; i2 < 4; ++i2)
#pragma unroll
            for (int im = 0; im < 4; ++im)
                acc2[i2][im] = mfma16(a2[i2], bh[im], acc2[i2][im]);
    }

    // ---- GEMM3: lamb[m] = sum_n2 relu(h2 + b2) * W3 (fp32, exact) ----
    float part[4] = {0.f, 0.f, 0.f, 0.f};
#pragma unroll
    for (int i2 = 0; i2 < 4; ++i2) {
        int n2b = 64 * w + i2 * 16 + q * 4;
#pragma unroll
        for (int im = 0; im < 4; ++im)
#pragma unroll
            for (int r = 0; r < 4; ++r) {
                float h2 = fmaxf(acc2[i2][im][r] + b2f[n2b + r], 0.f);
                part[im] = fmaf(h2, w3f[n2b + r], part[im]);
            }
    }
#pragma unroll
    for (int im = 0; im < 4; ++im) {
        float p = part[im];
        p += __shfl_xor(p, 16);
        p += __shfl_xor(p, 32);
        if (q == 0) lamb_part[w][im * 16 + L] = p;
    }
    __syncthreads();

    // ---- epilogue: one thread per row; S/I straight from x (L1-hot) ----
    if (tid < 64) {
        int gm = m0 + tid;
        float lam = lamb_part[0][tid] + lamb_part[1][tid] +
                    lamb_part[2][tid] + lamb_part[3][tid] + b3[0];
        const float2 si = *(const float2*)(x + (size_t)gm * 32);
        float S = si.x, I = si.y;
        int c = gm % C_CNT;
        float of = 1.0f - T[c * C_CNT + c];
        float sv = sinW[gm], iv = iinW[gm];
        float dS = -lam * S + sv - of * S;
        float dI =  lam * S + iv - of * I;
        float2 o; o.x = S + dS; o.y = I + dI;
        ((float2*)out)[gm] = o;   // coalesced 8B store -> out[2gm], out[2gm+1]
    }
}

// ---------------------------------------------------------------------------
extern "C" void kernel_launch(void* const* d_in, const int* in_sizes, int n_in,
                              void* d_out, int out_size, void* d_ws, size_t ws_size,
                              hipStream_t stream) {
    const float* x  = (const float*)d_in[0];
    const float* T  = (const float*)d_in[1];
    const float* W1 = (const float*)d_in[2];
    const float* b1 = (const float*)d_in[3];
    const float* W2 = (const float*)d_in[4];
    const float* b2 = (const float*)d_in[5];
    const float* W3 = (const float*)d_in[6];
    const float* b3 = (const float*)d_in[7];

    // ws layout: sinW iinW (2 x 1.64 MB), W1t (16 KB), W2t (128 KB) ~= 3.4 MB
    const size_t f32_arr = (size_t)M_ROWS * 4;
    char* ws = (char*)d_ws;
    float*  sinW = (float*)(ws);
    float*  iinW = (float*)(ws + f32_arr);
    ushort* W1t  = (ushort*)(ws + 2 * f32_arr);
    ushort* W2t  = (ushort*)(ws + 2 * f32_arr + 8192 * 2);

    hipLaunchKernelGGL(prep_kernel, dim3(PREP_MAIN + 256 + 32), dim3(256), 0, stream,
                       x, T, W1, W2, sinW, iinW, W1t, W2t);
    hipLaunchKernelGGL(mlp_kernel, dim3(M_ROWS / 64), dim3(256), 0, stream,
                       x, T, b1, b2, W3, b3, W1t, W2t, sinW, iinW,
                       (float*)d_out);
}

// Round 2
// 185.107 us; speedup vs baseline: 1.2887x; 1.2887x over previous
//
#include <hip/hip_runtime.h>
#include <stdint.h>

// Problem constants: B=2048, C=200, F=32, H=256. All tensors fp32 in/out.
// M = B*C = 409600 rows of 32 features, contiguous in x.
#define M_ROWS 409600
#define B_CNT  2048
#define C_CNT  200
#define N_TILES (M_ROWS / 64)    // 6400 tiles of 64 rows
#define GRID_MLP 512             // persistent blocks: 2 per CU

typedef __attribute__((ext_vector_type(8))) short bf16x8;   // 8 bf16 = 4 VGPRs
typedef __attribute__((ext_vector_type(4))) float f32x4;

// round-to-nearest-even f32 -> bf16 bits
__device__ __forceinline__ ushort f2bf(float f) {
    uint32_t u = __float_as_uint(f);
    u += 0x7fffu + ((u >> 16) & 1u);
    return (ushort)(u >> 16);
}

__device__ __forceinline__ f32x4 mfma16(bf16x8 a, bf16x8 b, f32x4 c) {
    return __builtin_amdgcn_mfma_f32_16x16x32_bf16(a, b, c, 0, 0, 0);
}

__device__ __forceinline__ bf16x8 pack8(float4 a, float4 b) {
    bf16x8 r;
    r[0] = (short)f2bf(a.x); r[1] = (short)f2bf(a.y);
    r[2] = (short)f2bf(a.z); r[3] = (short)f2bf(a.w);
    r[4] = (short)f2bf(b.x); r[5] = (short)f2bf(b.y);
    r[6] = (short)f2bf(b.z); r[7] = (short)f2bf(b.w);
    return r;
}

// ---------------------------------------------------------------------------
// Prep kernel — restored to the round-0 form (measured-good):
//   blocks [0,2048):   one coalesced pass over the x row: bf16 copy (xb16),
//                      exact S/I extraction (compact Sc/Ic), sinflow/iinflow
//   blocks [2048,2304): W2^T -> bf16  (coalesced writes)
//   blocks [2304,2336): W1^T -> bf16
// ---------------------------------------------------------------------------
__global__ __launch_bounds__(256) void prep_kernel(
    const float* __restrict__ x, const float* __restrict__ T,
    const float* __restrict__ W1, const float* __restrict__ W2,
    ushort* __restrict__ xb16, float* __restrict__ Sc, float* __restrict__ Ic,
    float* __restrict__ sinW, float* __restrict__ iinW,
    ushort* __restrict__ W1t, ushort* __restrict__ W2t, int do_xb) {
    int blk = blockIdx.x, t = threadIdx.x;
    if (blk < B_CNT) {
        __shared__ float Sr[C_CNT], Ir[C_CNT];
        const float4* xr = (const float4*)(x + (size_t)blk * 6400);  // 1600 f4
        ushort4* xw = (ushort4*)(xb16 + (size_t)blk * 6400);
#pragma unroll
        for (int i = 0; i < 7; ++i) {
            int i4 = i * 256 + t;
            if (i4 < 1600) {
                float4 v = xr[i4];
                if (do_xb) {
                    ushort4 u;
                    u.x = f2bf(v.x); u.y = f2bf(v.y);
                    u.z = f2bf(v.z); u.w = f2bf(v.w);
                    xw[i4] = u;
                }
                if ((i4 & 7) == 0) {           // element i4*4 is feature 0 of c
                    int c = i4 >> 3;
                    Sr[c] = v.x; Ir[c] = v.y;
                    Sc[blk * C_CNT + c] = v.x;
                    Ic[blk * C_CNT + c] = v.y;
                }
            }
        }
        __syncthreads();
        if (t < C_CNT) {
            float as = 0.f, ai = 0.f;
            for (int cp = 0; cp < C_CNT; ++cp) {
                float tv = T[cp * C_CNT + t];        // coalesced over t, L2-hot
                as = fmaf(Sr[cp], tv, as);
                ai = fmaf(Ir[cp], tv, ai);
            }
            sinW[blk * C_CNT + t] = as;
            iinW[blk * C_CNT + t] = ai;
        }
    } else if (blk < B_CNT + 256) {
        int n = blk - B_CNT;                          // one n2 row per block
        W2t[n * 256 + t] = f2bf(W2[t * 256 + n]);     // write coalesced
    } else {
        int idx = (blk - B_CNT - 256) * 256 + t;      // 0..8191
        int n = idx >> 5, k = idx & 31;
        W1t[idx] = f2bf(W1[k * 256 + n]);
    }
}

// ---------------------------------------------------------------------------
// Persistent fused MLP kernel. 512 blocks (2/CU), 4 waves each; each block
// loops over ~12.5 tiles of 64 rows. Per wave, its GEMM2 A-slice of W2t
// (64 n2-rows x 256 k = 32 KB = 128 VGPRs) and its W1t fragments are loaded
// ONCE and stay register-resident across tiles -> the inner loop has no
// global weight traffic: GEMM2 is ds_read_b128 + MFMA only.
// MFMA 16x16x32 frags: A[m=lane&15][k=q*8+j], B[k=q*8+j][n=lane&15],
// C/D col=lane&15, row=q*4+reg.
// ---------------------------------------------------------------------------
template <bool XB>
__global__ __launch_bounds__(256, 2) void mlp_kernel(
    const float* __restrict__ x,
    const ushort* __restrict__ xb16,
    const float* __restrict__ T,
    const float* __restrict__ b1,
    const float* __restrict__ b2,
    const float* __restrict__ W3,
    const float* __restrict__ b3,
    const ushort* __restrict__ W1t,   // [256][32]  bf16, n1-major
    const ushort* __restrict__ W2t,   // [256][256] bf16, n2-major
    const float* __restrict__ Sc, const float* __restrict__ Ic,
    const float* __restrict__ sinW, const float* __restrict__ iinW,
    float* __restrict__ out) {
    constexpr int RS = 264;  // h1 row stride: 256+8, rows 16B-aligned, pad kills conflicts
    __shared__ ushort h1s[64 * RS];          // 33792 B
    __shared__ float b1f[256], b2f[256], w3f[256];
    __shared__ float lamb_part[4][64];

    const int tid  = threadIdx.x;
    const int w    = tid >> 6;
    const int lane = tid & 63;
    const int L    = lane & 15;
    const int q    = lane >> 4;

    b1f[tid] = b1[tid];
    b2f[tid] = b2[tid];
    w3f[tid] = W3[tid];
    const float b3v = b3[0];

    // ---- register-resident weights (loaded once, reused every tile) ----
    bf16x8 a2r[4][8];                 // [i2][kc] : this wave's W2t slice, 128 VGPRs
#pragma unroll
    for (int i2 = 0; i2 < 4; ++i2)
#pragma unroll
        for (int kc = 0; kc < 8; ++kc)
            a2r[i2][kc] =
                *(const bf16x8*)(W2t + (64 * w + i2 * 16 + L) * 256 + kc * 32 + q * 8);

    bf16x8 aw[4];                     // W1t fragments, 16 VGPRs
#pragma unroll
    for (int i = 0; i < 4; ++i)
        aw[i] = *(const bf16x8*)(W1t + (64 * w + i * 16 + L) * 32 + q * 8);

    for (int tile = blockIdx.x; tile < N_TILES; tile += GRID_MLP) {
        const int m0 = tile * 64;

        // ---- GEMM1 (K=32): B from bf16 xb16 (or fp32 x + pack) ----
        bf16x8 bx[4];
#pragma unroll
        for (int i = 0; i < 4; ++i) {
            if (XB) {
                bx[i] = *(const bf16x8*)(xb16 + (size_t)(m0 + i * 16 + L) * 32 + q * 8);
            } else {
                const float4* xr =
                    (const float4*)(x + (size_t)(m0 + i * 16 + L) * 32 + q * 8);
                bx[i] = pack8(xr[0], xr[1]);
            }
        }
        f32x4 acc1[4][4];
#pragma unroll
        for (int i1 = 0; i1 < 4; ++i1)
#pragma unroll
            for (int im = 0; im < 4; ++im)
                acc1[i1][im] = mfma16(aw[i1], bx[im], (f32x4){0.f, 0.f, 0.f, 0.f});

        // barrier A: previous tile's GEMM2 h1s reads all done; b1f visible (iter 0)
        __syncthreads();

        // fp32 bias + relu, one bf16 rounding; 4 consecutive n1 -> ds_write_b64
#pragma unroll
        for (int i1 = 0; i1 < 4; ++i1) {
            int n1b = 64 * w + i1 * 16 + q * 4;
#pragma unroll
            for (int im = 0; im < 4; ++im) {
                int m = im * 16 + L;
                float v0 = fmaxf(acc1[i1][im][0] + b1f[n1b + 0], 0.f);
                float v1 = fmaxf(acc1[i1][im][1] + b1f[n1b + 1], 0.f);
                float v2 = fmaxf(acc1[i1][im][2] + b1f[n1b + 2], 0.f);
                float v3 = fmaxf(acc1[i1][im][3] + b1f[n1b + 3], 0.f);
                uint2 pk;
                pk.x = (uint32_t)f2bf(v0) | ((uint32_t)f2bf(v1) << 16);
                pk.y = (uint32_t)f2bf(v2) | ((uint32_t)f2bf(v3) << 16);
                *reinterpret_cast<uint2*>(&h1s[m * RS + n1b]) = pk;
            }
        }
        __syncthreads();   // barrier B: h1s ready

        // ---- GEMM2 (K=256, 8 k-chunks): A from registers, B from LDS ----
        f32x4 acc2[4][4];
#pragma unroll
        for (int i2 = 0; i2 < 4; ++i2)
#pragma unroll
            for (int im = 0; im < 4; ++im) acc2[i2][im] = (f32x4){0.f, 0.f, 0.f, 0.f};

#pragma unroll
        for (int kc = 0; kc < 8; ++kc) {
            bf16x8 bh[4];
#pragma unroll
            for (int im = 0; im < 4; ++im) {
                int m = im * 16 + L;
                bh[im] = *(const bf16x8*)(&h1s[m * RS + kc * 32 + q * 8]);  // ds_read_b128
            }
#pragma unroll
            for (int i2 = 0; i2 < 4; ++i2)
#pragma unroll
                for (int im = 0; im < 4; ++im)
                    acc2[i2][im] = mfma16(a2r[i2][kc], bh[im], acc2[i2][im]);
        }

        // ---- GEMM3: lamb[m] = sum_n2 relu(h2 + b2) * W3 (fp32, exact) ----
        float part[4] = {0.f, 0.f, 0.f, 0.f};
#pragma unroll
        for (int i2 = 0; i2 < 4; ++i2) {
            int n2b = 64 * w + i2 * 16 + q * 4;
#pragma unroll
            for (int im = 0; im < 4; ++im)
#pragma unroll
                for (int r = 0; r < 4; ++r) {
                    float h2 = fmaxf(acc2[i2][im][r] + b2f[n2b + r], 0.f);
                    part[im] = fmaf(h2, w3f[n2b + r], part[im]);
                }
        }
#pragma unroll
        for (int im = 0; im < 4; ++im) {
            float p = part[im];
            p += __shfl_xor(p, 16);
            p += __shfl_xor(p, 32);
            if (q == 0) lamb_part[w][im * 16 + L] = p;
        }
        __syncthreads();   // barrier C: lamb_part ready

        // ---- epilogue: one thread per row, all reads compact & coalesced ----
        if (tid < 64) {
            int gm = m0 + tid;
            float lam = lamb_part[0][tid] + lamb_part[1][tid] +
                        lamb_part[2][tid] + lamb_part[3][tid] + b3v;
            float S = Sc[gm], I = Ic[gm];
            int c = gm % C_CNT;
            float of = 1.0f - T[c * C_CNT + c];
            float sv = sinW[gm], iv = iinW[gm];
            float dS = -lam * S + sv - of * S;
            float dI =  lam * S + iv - of * I;
            float2 o; o.x = S + dS; o.y = I + dI;
            ((float2*)out)[gm] = o;   // coalesced 8B store -> out[2gm], out[2gm+1]
        }
        // next iteration's barrier A protects h1s reuse; lamb_part reuse is
        // protected because barrier A+B precede the next lamb write.
    }
}

// ---------------------------------------------------------------------------
extern "C" void kernel_launch(void* const* d_in, const int* in_sizes, int n_in,
                              void* d_out, int out_size, void* d_ws, size_t ws_size,
                              hipStream_t stream) {
    const float* x  = (const float*)d_in[0];
    const float* T  = (const float*)d_in[1];
    const float* W1 = (const float*)d_in[2];
    const float* b1 = (const float*)d_in[3];
    const float* W2 = (const float*)d_in[4];
    const float* b2 = (const float*)d_in[5];
    const float* W3 = (const float*)d_in[6];
    const float* b3 = (const float*)d_in[7];

    // ws layout: [xb16 (opt, 26.2 MB)] Sc Ic sin iin (4x1.64 MB) W1t W2t (144KB)
    const size_t xb_bytes = (size_t)M_ROWS * 32 * 2;
    const size_t f32_arr  = (size_t)M_ROWS * 4;
    const size_t small    = 4 * f32_arr + 8192 * 2 + 65536 * 2;
    const int    do_xb    = (ws_size >= xb_bytes + small) ? 1 : 0;

    char* ws = (char*)d_ws;
    ushort* xb16 = (ushort*)ws;
    char* base = ws + (do_xb ? xb_bytes : 0);
    float*  Sc   = (float*)(base);
    float*  Ic   = (float*)(base + f32_arr);
    float*  sinW = (float*)(base + 2 * f32_arr);
    float*  iinW = (float*)(base + 3 * f32_arr);
    ushort* W1t  = (ushort*)(base + 4 * f32_arr);
    ushort* W2t  = (ushort*)(base + 4 * f32_arr + 8192 * 2);

    hipLaunchKernelGGL(prep_kernel, dim3(B_CNT + 256 + 32), dim3(256), 0, stream,
                       x, T, W1, W2, xb16, Sc, Ic, sinW, iinW, W1t, W2t, do_xb);
    if (do_xb) {
        hipLaunchKernelGGL((mlp_kernel<true>), dim3(GRID_MLP), dim3(256), 0, stream,
                           x, xb16, T, b1, b2, W3, b3, W1t, W2t, Sc, Ic, sinW, iinW,
                           (float*)d_out);
    } else {
        hipLaunchKernelGGL((mlp_kernel<false>), dim3(GRID_MLP), dim3(256), 0, stream,
                           x, xb16, T, b1, b2, W3, b3, W1t, W2t, Sc, Ic, sinW, iinW,
                           (float*)d_out);
    }
}